// Round 5
// baseline (642.036 us; speedup 1.0000x reference)
//
#include <hip/hip_runtime.h>
#include <math.h>

// Problem dims (fixed by reference)
#define B_   4
#define L_   1024
#define D_   512
#define CHI_ 32
#define S_   4
#define BT_  (B_ * L_)          // 4096 rows
#define NC_  2560               // fused GEMM width: 1024 AbarI | 1024 G | 512 gate
#define DPRE 8                  // scan prefetch distance (LDS ring, slots ahead)
#define SLOTS 16                // LDS ring slots (power of 2, > DPRE+1)
#define SLOT_F 1088             // floats per slot: 1024 A + 64 c pad

// ---------------------------------------------------------------------------
// Cross-lane helpers
// ---------------------------------------------------------------------------
__device__ __forceinline__ float bpermute_f(int byte_idx, float v) {
    return __int_as_float(__builtin_amdgcn_ds_bpermute(byte_idx, __float_as_int(v)));
}

template <int CTRL>
__device__ __forceinline__ float dpp_add(float x) {
    int y = __builtin_amdgcn_update_dpp(0, __float_as_int(x), CTRL, 0xf, 0xf, true);
    return x + __int_as_float(y);
}

// Octet sum; complete sum lands in the TOP lane of each octet ((lane&7)==7).
__device__ __forceinline__ float octet_sum(float x) {
    x = dpp_add<0x111>(x);
    x = dpp_add<0x112>(x);
    x = dpp_add<0x114>(x);
    return x;
}

// Octet BUTTERFLY sum over consecutive 8-lane groups: xor1 (quad_perm
// [1,0,3,2]), xor2 (quad_perm [2,3,0,1]), mirror (row_half_mirror == xor7
// within each 8-lane half-row). Result lands in ALL 8 lanes of the octet.
__device__ __forceinline__ float octet_bfly(float x) {
    x = dpp_add<0xB1>(x);    // quad_perm [1,0,3,2]  = xor 1
    x = dpp_add<0x4E>(x);    // quad_perm [2,3,0,1]  = xor 2
    x = dpp_add<0x141>(x);   // row_half_mirror       = xor 7 (completes octet)
    return x;
}

// ---------------------------------------------------------------------------
// Buffer resource descriptor (SRD) for bounds-checked MUBUF stores.
// ---------------------------------------------------------------------------
typedef __attribute__((ext_vector_type(4))) unsigned int srd_t;

__device__ __forceinline__ srd_t make_srd(const void* p, unsigned bytes) {
    const unsigned long long a = (unsigned long long)p;
    srd_t r;
    r.x = (unsigned)a;
    r.y = (unsigned)(a >> 32);     // stride bits [29:16] = 0
    r.z = bytes;                   // num_records (bytes, stride==0)
    r.w = 0x00020000u;             // raw untyped dword access
    return r;
}

// ---------------------------------------------------------------------------
// Async global->LDS copies (no VGPR destination -> no async-register hazard).
// LDS dest = wave-uniform base + lane*width; global src is per-lane.
// ---------------------------------------------------------------------------
typedef __attribute__((address_space(1))) const void gas1_void;
typedef __attribute__((address_space(3))) void las3_void;

__device__ __forceinline__ void gl_lds16(const float* g, float* l) {
    __builtin_amdgcn_global_load_lds((gas1_void*)g, (las3_void*)l, 16, 0, 0);
}
__device__ __forceinline__ void gl_lds4(const float* g, float* l) {
    __builtin_amdgcn_global_load_lds((gas1_void*)g, (las3_void*)l, 4, 0, 0);
}

// ---------------------------------------------------------------------------
// buildW: fold W_site with (sum_p ·) and with W_bridge; append W_gate.
//   Wcomb[d][f], f in [0,1024):    WA_perm  (scan-interleaved Abar columns)
//   f in [1024,2048):              WW[l*32+j] = sum_pr Ws[d,l*128+pr]*Wb[pr,j]
//   f in [2048,2560):              W_gate[d][f-2048]
// Block 512 == bias block (same folds applied to b_site / b_gate).
// Interleave map: f = 256q+4i+e  ->  l = 4*(i&7)+e,  r = (i>>3)+8q.
// ---------------------------------------------------------------------------
__global__ __launch_bounds__(256) void buildW_kernel(
    const float* __restrict__ Ws, const float* __restrict__ bs,
    const float* __restrict__ Wb, const float* __restrict__ Wg,
    const float* __restrict__ bg, float* __restrict__ Wcomb,
    float* __restrict__ biasC)
{
    const int tid = threadIdx.x;

    if (blockIdx.x == 512) {   // bias block
        for (int f = tid; f < NC_; f += 256) {
            float acc;
            if (f < 1024) {
                const int q = f >> 8, rem = f & 255, i = rem >> 2, e = rem & 3;
                const int l = 4 * (i & 7) + e, r = (i >> 3) + 8 * q;
                const float* p = bs + l * 128 + r;
                acc = p[0] + p[32] + p[64] + p[96];
            } else if (f < 2048) {
                const int g = f - 1024, l = g >> 5, j = g & 31;
                acc = 0.f;
                for (int pr = 0; pr < 128; ++pr)
                    acc = fmaf(bs[l * 128 + pr], Wb[pr * 32 + j], acc);
            } else {
                acc = bg[f - 2048];
            }
            biasC[f] = acc;
        }
        return;
    }

    __shared__ float wsrow[4096];
    __shared__ float wbs[4096];    // Wb[pr][j], pr*32+j

    const int d = blockIdx.x;
    #pragma unroll
    for (int i = 0; i < 16; ++i) {
        wsrow[i * 256 + tid] = Ws[(size_t)d * 4096 + i * 256 + tid];
        wbs[i * 256 + tid]   = Wb[i * 256 + tid];
    }
    __syncthreads();

    float* wrow = Wcomb + (size_t)d * NC_;

    // WA (interleaved): 4 cols/thread
    #pragma unroll
    for (int ii = 0; ii < 4; ++ii) {
        const int f = ii * 256 + tid;
        const int q = f >> 8, rem = f & 255, i = rem >> 2, e = rem & 3;
        const int l = 4 * (i & 7) + e, r = (i >> 3) + 8 * q;
        const float* p = wsrow + l * 128 + r;
        wrow[f] = p[0] + p[32] + p[64] + p[96];
    }
    // WW: 4 cols/thread, 128 FMA each
    #pragma unroll
    for (int ii = 0; ii < 4; ++ii) {
        const int g = ii * 256 + tid;
        const int l = g >> 5, j = g & 31;
        float acc = 0.f;
        #pragma unroll 8
        for (int pr = 0; pr < 128; ++pr)
            acc = fmaf(wsrow[l * 128 + pr], wbs[pr * 32 + j], acc);
        wrow[1024 + g] = acc;
    }
    // gate copy: 2 cols/thread
    #pragma unroll
    for (int ii = 0; ii < 2; ++ii) {
        const int c = ii * 256 + tid;
        wrow[2048 + c] = Wg[(size_t)d * 512 + c];
    }
}

// ---------------------------------------------------------------------------
// Generic fp32 GEMM with bias: C[M,N] = A[M,K] @ B[K,N] + bias[N]
// ---------------------------------------------------------------------------
__global__ __launch_bounds__(256) void gemm_bias_kernel(
    const float* __restrict__ A, const float* __restrict__ Bm,
    const float* __restrict__ bias, float* __restrict__ C,
    int M, int N, int K)
{
    __shared__ float As[32][68];
    __shared__ float Bs[32][64];

    const int tid = threadIdx.x;
    const int tx = tid & 15;
    const int ty = tid >> 4;
    const int m0 = blockIdx.y * 64;
    const int n0 = blockIdx.x * 64;

    float c[4][4] = {};

    for (int k0 = 0; k0 < K; k0 += 32) {
        {
            const int o = tid * 8;
            const int m = o >> 5;
            const int k = o & 31;
            const float* ap = A + (size_t)(m0 + m) * K + k0 + k;
            const float4 a0 = *(const float4*)ap;
            const float4 a1 = *(const float4*)(ap + 4);
            As[k + 0][m] = a0.x; As[k + 1][m] = a0.y;
            As[k + 2][m] = a0.z; As[k + 3][m] = a0.w;
            As[k + 4][m] = a1.x; As[k + 5][m] = a1.y;
            As[k + 6][m] = a1.z; As[k + 7][m] = a1.w;
        }
        {
            const int o = tid * 8;
            const int k = o >> 6;
            const int n = o & 63;
            const float* bp = Bm + (size_t)(k0 + k) * N + n0 + n;
            *(float4*)&Bs[k][n]     = *(const float4*)bp;
            *(float4*)&Bs[k][n + 4] = *(const float4*)(bp + 4);
        }
        __syncthreads();

        #pragma unroll
        for (int kk = 0; kk < 32; ++kk) {
            const float4 av = *(const float4*)&As[kk][ty * 4];
            const float4 bv = *(const float4*)&Bs[kk][tx * 4];
            const float a[4] = {av.x, av.y, av.z, av.w};
            const float b[4] = {bv.x, bv.y, bv.z, bv.w};
            #pragma unroll
            for (int i = 0; i < 4; ++i)
                #pragma unroll
                for (int j = 0; j < 4; ++j)
                    c[i][j] = fmaf(a[i], b[j], c[i][j]);
        }
        __syncthreads();
    }

    const float4 bv = *(const float4*)&bias[n0 + tx * 4];
    #pragma unroll
    for (int i = 0; i < 4; ++i) {
        float4 outv;
        outv.x = c[i][0] + bv.x;
        outv.y = c[i][1] + bv.y;
        outv.z = c[i][2] + bv.z;
        outv.w = c[i][3] + bv.w;
        *(float4*)&C[(size_t)(m0 + ty * 4 + i) * N + n0 + tx * 4] = outv;
    }
}

// ---------------------------------------------------------------------------
// cvec: c[bt][r] = sum_l u[l]*Abar[l][r], u = x[bt,0:32]. AbarI is the
// interleaved block at C[bt*NC_ + 0..1024). One wave per bt.
// ---------------------------------------------------------------------------
__global__ __launch_bounds__(256) void cvec_kernel(
    const float* __restrict__ Cc, const float* __restrict__ x,
    float* __restrict__ cBuf)
{
    const int tid  = threadIdx.x;
    const int lane = tid & 63;
    const int bt   = blockIdx.x * 4 + (tid >> 6);

    const float* base = Cc + (size_t)bt * NC_ + 4 * lane;
    float4 a0 = *(const float4*)(base + 0);
    float4 a1 = *(const float4*)(base + 256);
    float4 a2 = *(const float4*)(base + 512);
    float4 a3 = *(const float4*)(base + 768);

    const float u = x[(size_t)bt * D_ + (lane & 31)];
    const int idx0 = 16 * (lane & 7);
    const float u0 = bpermute_f(idx0 + 0,  u);
    const float u1 = bpermute_f(idx0 + 4,  u);
    const float u2 = bpermute_f(idx0 + 8,  u);
    const float u3 = bpermute_f(idx0 + 12, u);

    float p0 = fmaf(u3, a0.w, fmaf(u2, a0.z, fmaf(u1, a0.y, u0 * a0.x)));
    float p1 = fmaf(u3, a1.w, fmaf(u2, a1.z, fmaf(u1, a1.y, u0 * a1.x)));
    float p2 = fmaf(u3, a2.w, fmaf(u2, a2.z, fmaf(u1, a2.y, u0 * a2.x)));
    float p3 = fmaf(u3, a3.w, fmaf(u2, a3.z, fmaf(u1, a3.y, u0 * a3.x)));

    p0 = octet_sum(p0); p1 = octet_sum(p1);
    p2 = octet_sum(p2); p3 = octet_sum(p3);

    if ((lane & 7) == 7) {          // top lane of octet k holds m[k+8q]
        const int k = lane >> 3;
        float* cp = cBuf + (size_t)bt * 32 + k;
        cp[0]  = p0;
        cp[8]  = p1;
        cp[16] = p2;
        cp[24] = p3;
    }
}

// ---------------------------------------------------------------------------
// Serial scan, broadcast-layout state + LDS prefetch ring.
//
// State: lane (h = tid&7) permanently holds wb_i = w[4h+i], i=0..3 (each
// consecutive-8-lane octet k covers l-blocks h=0..7 for column r = k+8q).
// Per step: nn = octet_bfly(sum wb^2) (all lanes); p_q = partials;
// octet_bfly(p_q) -> m[k+8q]; pack rp = p_{tid&3}; one bpermute round
// gathers m[4h+i]; wb_i <- m_i*rn + c_i. Normalized h_t stored (asm).
//
// Prefetch: 16-slot LDS ring (slot = 1024 A floats + 64 c floats), filled
// DPRE=8 steps ahead via global_load_lds (5 vmem ops/step: 4x16B + 1x4B).
// No VGPR load destinations -> no async-register hazard. Counted vmcnt
// (never 0): peel steps 0..7 wait 35+2t, steady wait 49 (peak 56 < 63).
// sched_barrier(0) fences pin [issue][wait][read+compute+stores] order so
// the vmem FIFO arithmetic is exact. ds_reads of slot t+1 are compiler-
// managed (correct lgkmcnt by construction), overlapped with step-t compute.
// Tail issues (t+8 > 1023) read a few rows past the region (still inside
// d_ws; data never consumed).
// ---------------------------------------------------------------------------
#define SCAN_STEP(TT, W)                                                        \
    do {                                                                        \
        const int t_is = (TT) + DPRE;                                           \
        {                                                                       \
            float* sl = ldsb + (t_is & (SLOTS - 1)) * SLOT_F;                   \
            const float* ar = Abase + (size_t)t_is * NC_ + 4 * tid;             \
            gl_lds16(ar,       sl);                                             \
            gl_lds16(ar + 256, sl + 256);                                       \
            gl_lds16(ar + 512, sl + 512);                                       \
            gl_lds16(ar + 768, sl + 768);                                       \
            gl_lds4(cbase + (size_t)t_is * 32 + tid, sl + 1024);                \
        }                                                                       \
        __builtin_amdgcn_sched_barrier(0);                                      \
        asm volatile("s_waitcnt vmcnt(" W ")");                                 \
        __builtin_amdgcn_sched_barrier(0);                                      \
        const float* sr = ldsb + (((TT) + 1) & (SLOTS - 1)) * SLOT_F;           \
        const float4 nA0 = *(const float4*)(sr + 4 * tid);                      \
        const float4 nA1 = *(const float4*)(sr + 256 + 4 * tid);                \
        const float4 nA2 = *(const float4*)(sr + 512 + 4 * tid);                \
        const float4 nA3 = *(const float4*)(sr + 768 + 4 * tid);                \
        const float4 nC  = *(const float4*)(sr + 1024 + 4 * h);                 \
        float nn = fmaf(wb1, wb1, wb0 * wb0)                                    \
                 + fmaf(wb3, wb3, wb2 * wb2);                                   \
        nn = octet_bfly(nn);                                                    \
        const float rn = rsqrtf(nn + 1e-24f);                                   \
        float p0 = fmaf(wb1, cA0.y, wb0 * cA0.x)                                \
                 + fmaf(wb3, cA0.w, wb2 * cA0.z);                               \
        float p1 = fmaf(wb1, cA1.y, wb0 * cA1.x)                                \
                 + fmaf(wb3, cA1.w, wb2 * cA1.z);                               \
        float p2 = fmaf(wb1, cA2.y, wb0 * cA2.x)                                \
                 + fmaf(wb3, cA2.w, wb2 * cA2.z);                               \
        float p3 = fmaf(wb1, cA3.y, wb0 * cA3.x)                                \
                 + fmaf(wb3, cA3.w, wb2 * cA3.z);                               \
        p0 = octet_bfly(p0);                                                    \
        p1 = octet_bfly(p1);                                                    \
        p2 = octet_bfly(p2);                                                    \
        p3 = octet_bfly(p3);                                                    \
        const float rp = (tid & 2) ? ((tid & 1) ? p3 : p2)                      \
                                   : ((tid & 1) ? p1 : p0);                     \
        const float m0 = bpermute_f(idx0,      rp);                             \
        const float m1 = bpermute_f(idx0 + 32, rp);                             \
        const float m2 = bpermute_f(idx0 + 64, rp);                             \
        const float m3 = bpermute_f(idx0 + 96, rp);                             \
        const unsigned long long s01 =                                          \
            ((unsigned long long)__float_as_uint(wb1 * rn) << 32) |             \
            (unsigned)__float_as_uint(wb0 * rn);                                \
        const unsigned long long s23 =                                          \
            ((unsigned long long)__float_as_uint(wb3 * rn) << 32) |             \
            (unsigned)__float_as_uint(wb2 * rn);                                \
        asm volatile("buffer_store_dwordx2 %1, %0, %2, 0 offen"                 \
                     :: "v"(voffW), "v"(s01), "s"(srdW));                       \
        asm volatile("buffer_store_dwordx2 %1, %0, %2, 0 offen offset:8"        \
                     :: "v"(voffW), "v"(s23), "s"(srdW));                       \
        voffW += 128u;                                                          \
        wb0 = fmaf(m0, rn, cC.x);                                               \
        wb1 = fmaf(m1, rn, cC.y);                                               \
        wb2 = fmaf(m2, rn, cC.z);                                               \
        wb3 = fmaf(m3, rn, cC.w);                                               \
        cA0 = nA0; cA1 = nA1; cA2 = nA2; cA3 = nA3; cC = nC;                    \
        __builtin_amdgcn_sched_barrier(0);                                      \
    } while (0)

__global__ __launch_bounds__(64, 1) void scan_kernel(
    const float* __restrict__ Cc, const float* __restrict__ cBuf,
    float* __restrict__ hnOut)
{
    __shared__ __align__(16) float ldsb[SLOTS * SLOT_F];   // 69,632 B

    const int b   = blockIdx.x;
    const int tid = threadIdx.x;            // 0..63
    const int h   = tid & 7;

    const float* Abase = Cc   + (size_t)b * L_ * NC_;
    const float* cbase = cBuf + (size_t)b * L_ * 32;
    const srd_t  srdW  = make_srd(hnOut + (size_t)b * L_ * 32,
                                  (unsigned)(L_ * 32 * 4));

    // bpermute byte index: m[4h+i] lives at source lane 32*(h&1)+8*i+(h>>1)
    const int idx0 = 4 * (32 * (h & 1) + (h >> 1));

    unsigned voffW = (unsigned)(h * 16);

    // prologue: fill slots 0..7 (40 vmem ops)
    #pragma unroll
    for (int j = 0; j < DPRE; ++j) {
        float* sl = ldsb + j * SLOT_F;
        const float* ar = Abase + (size_t)j * NC_ + 4 * tid;
        gl_lds16(ar,       sl);
        gl_lds16(ar + 256, sl + 256);
        gl_lds16(ar + 512, sl + 512);
        gl_lds16(ar + 768, sl + 768);
        gl_lds4(cbase + (size_t)j * 32 + tid, sl + 1024);
    }
    __builtin_amdgcn_sched_barrier(0);
    asm volatile("s_waitcnt vmcnt(35)");     // slot 0 resident
    __builtin_amdgcn_sched_barrier(0);

    float4 cA0 = *(const float4*)(ldsb + 4 * tid);
    float4 cA1 = *(const float4*)(ldsb + 256 + 4 * tid);
    float4 cA2 = *(const float4*)(ldsb + 512 + 4 * tid);
    float4 cA3 = *(const float4*)(ldsb + 768 + 4 * tid);
    float4 cC  = *(const float4*)(ldsb + 1024 + 4 * h);

    float wb0 = 0.f, wb1 = 0.f, wb2 = 0.f, wb3 = 0.f;   // w_0 = 0

    // peeled first 8 steps (prologue-exact waits)
    SCAN_STEP(0, "35");
    SCAN_STEP(1, "37");
    SCAN_STEP(2, "39");
    SCAN_STEP(3, "41");
    SCAN_STEP(4, "43");
    SCAN_STEP(5, "45");
    SCAN_STEP(6, "47");
    SCAN_STEP(7, "49");

    for (int t = DPRE; t < L_; t += DPRE) {
        SCAN_STEP(t + 0, "49");
        SCAN_STEP(t + 1, "49");
        SCAN_STEP(t + 2, "49");
        SCAN_STEP(t + 3, "49");
        SCAN_STEP(t + 4, "49");
        SCAN_STEP(t + 5, "49");
        SCAN_STEP(t + 6, "49");
        SCAN_STEP(t + 7, "49");
    }
    asm volatile("s_waitcnt vmcnt(0)");
}
#undef SCAN_STEP

// ---------------------------------------------------------------------------
// Phase B: left = hn + u (hn already normalized by the scan);
// y1[j] = sum_l left[l]*G[l*32+j] + bb[j], G = C[bt*NC_ + 1024..2048).
// ---------------------------------------------------------------------------
__global__ __launch_bounds__(128) void phaseB_kernel(
    const float* __restrict__ Cc, const float* __restrict__ x,
    const float* __restrict__ hnBuf, const float* __restrict__ bb,
    float* __restrict__ y1)
{
    __shared__ float lf[32];
    __shared__ float part[4][32];

    const int bt = blockIdx.x;
    const int tid = threadIdx.x;

    if (tid < 32)
        lf[tid] = hnBuf[(size_t)bt * 32 + tid] + x[(size_t)bt * D_ + tid];
    __syncthreads();

    const int j = tid & 31, q = tid >> 5;
    const float* Gp = Cc + (size_t)bt * NC_ + 1024;
    float p = 0.f;
    #pragma unroll
    for (int i = 0; i < 8; ++i)
        p = fmaf(lf[8 * q + i], Gp[(8 * q + i) * 32 + j], p);
    part[q][j] = p;
    __syncthreads();

    if (tid < 32)
        y1[bt * 32 + tid] = part[0][tid] + part[1][tid] + part[2][tid]
                          + part[3][tid] + bb[tid];
}

// ---------------------------------------------------------------------------
// Epilogue: y = y1 @ W_out + b_out; LayerNorm; gated residual with x.
// gate logits live in C[bt*NC_ + 2048 ..2560).
// ---------------------------------------------------------------------------
__global__ __launch_bounds__(256) void epilogue_kernel(
    const float* __restrict__ x, const float* __restrict__ y1buf,
    const float* __restrict__ Wout, const float* __restrict__ bout,
    const float* __restrict__ gamma, const float* __restrict__ beta,
    const float* __restrict__ Cc, float* __restrict__ out)
{
    __shared__ float ys[32];
    __shared__ float red1[4], red2[4];

    const int bt = blockIdx.x;
    const int tid = threadIdx.x;

    if (tid < 32) ys[tid] = y1buf[bt * 32 + tid];
    __syncthreads();

    float yv[2];
    #pragma unroll
    for (int q = 0; q < 2; ++q) {
        const int d = tid + q * 256;
        float acc = bout[d];
        #pragma unroll
        for (int j = 0; j < 32; ++j)
            acc = fmaf(ys[j], Wout[j * D_ + d], acc);
        yv[q] = acc;
    }

    float s1 = yv[0] + yv[1];
    float s2 = yv[0] * yv[0] + yv[1] * yv[1];
    #pragma unroll
    for (int m = 1; m <= 32; m <<= 1) {
        s1 += __shfl_xor(s1, m);
        s2 += __shfl_xor(s2, m);
    }
    const int wid = tid >> 6;
    if ((tid & 63) == 0) { red1[wid] = s1; red2[wid] = s2; }
    __syncthreads();
    const float S1 = red1[0] + red1[1] + red1[2] + red1[3];
    const float S2 = red2[0] + red2[1] + red2[2] + red2[3];
    const float mu  = S1 * (1.f / (float)D_);
    const float var = S2 * (1.f / (float)D_) - mu * mu;
    const float rstd = rsqrtf(var + 1e-6f);

    #pragma unroll
    for (int q = 0; q < 2; ++q) {
        const int d = tid + q * 256;
        const size_t gi = (size_t)bt * D_ + d;
        const float yn = (yv[q] - mu) * rstd * gamma[d] + beta[d];
        const float z = Cc[(size_t)bt * NC_ + 2048 + d];
        const float g = 1.f / (1.f + expf(-z));
        const float xv = x[gi];
        out[gi] = g * yn + (1.f - g) * xv;
    }
}

// ---------------------------------------------------------------------------
extern "C" void kernel_launch(void* const* d_in, const int* in_sizes, int n_in,
                              void* d_out, int out_size, void* d_ws, size_t ws_size,
                              hipStream_t stream)
{
    const float* x        = (const float*)d_in[0];
    const float* W_site   = (const float*)d_in[1];
    const float* b_site   = (const float*)d_in[2];
    const float* W_bridge = (const float*)d_in[3];
    const float* b_bridge = (const float*)d_in[4];
    const float* W_out    = (const float*)d_in[5];
    const float* b_out    = (const float*)d_in[6];
    const float* gamma    = (const float*)d_in[7];
    const float* beta     = (const float*)d_in[8];
    const float* W_gate   = (const float*)d_in[9];
    const float* b_gate   = (const float*)d_in[10];
    float* out = (float*)d_out;

    float* ws = (float*)d_ws;
    float* Wcomb = ws;                            //   512*2560 = 1,310,720 f
    float* biasC = Wcomb + (size_t)512 * NC_;     //        2,560 f
    float* Cc    = biasC + NC_;                   // 4096*2560 = 10,485,760 f (42 MB)
    float* cBuf  = Cc    + (size_t)BT_ * NC_;     //      131,072 f
    float* hnBuf = cBuf  + (size_t)BT_ * 32;      //      131,072 f (normalized h_t)
    float* y1    = hnBuf + (size_t)BT_ * 32;      //      131,072 f

    // 0. fold weights: [WA_perm | WW | W_gate] + fused bias
    buildW_kernel<<<dim3(513), dim3(256), 0, stream>>>(
        W_site, b_site, W_bridge, W_gate, b_gate, Wcomb, biasC);

    // 1. one fused GEMM: C = x @ Wcomb + biasC   [4096 x 2560, K=512]
    gemm_bias_kernel<<<dim3(NC_ / 64, BT_ / 64), dim3(256), 0, stream>>>(
        x, Wcomb, biasC, Cc, BT_, NC_, D_);

    // 2. c vectors: c = u . Abar  (fully parallel)
    cvec_kernel<<<dim3(BT_ / 4), dim3(256), 0, stream>>>(Cc, x, cBuf);

    // 3. serial scan (4 waves total) -> normalized h_t
    scan_kernel<<<dim3(B_), dim3(64), 0, stream>>>(Cc, cBuf, hnBuf);

    // 4. phase B: y1 = (hn + u) . G + bb
    phaseB_kernel<<<dim3(BT_), dim3(128), 0, stream>>>(
        Cc, x, hnBuf, b_bridge, y1);

    // 5. epilogue: out-proj + LN + gated residual (gate from C)
    epilogue_kernel<<<dim3(BT_), dim3(256), 0, stream>>>(
        x, y1, W_out, b_out, gamma, beta, Cc, out);
}

// Round 6
// 504.442 us; speedup vs baseline: 1.2728x; 1.2728x over previous
//
#include <hip/hip_runtime.h>
#include <math.h>

// Problem dims (fixed by reference)
#define B_   4
#define L_   1024
#define D_   512
#define CHI_ 32
#define S_   4
#define BT_  (B_ * L_)          // 4096 rows
#define NC_  2560               // fused GEMM width: 1024 AbarI | 1024 G | 512 gate
#define DPRE 8                  // scan prefetch distance (LDS ring, slots ahead)
#define SLOTS 16                // LDS ring slots (power of 2, > DPRE)
#define SLOT_F 1088             // floats per slot: 1024 A + 64 c

// ---------------------------------------------------------------------------
// Cross-lane helpers
// ---------------------------------------------------------------------------
__device__ __forceinline__ float bpermute_f(int byte_idx, float v) {
    return __int_as_float(__builtin_amdgcn_ds_bpermute(byte_idx, __float_as_int(v)));
}

template <int CTRL>
__device__ __forceinline__ float dpp_add(float x) {
    int y = __builtin_amdgcn_update_dpp(0, __float_as_int(x), CTRL, 0xf, 0xf, true);
    return x + __int_as_float(y);
}

// Octet sum; complete sum lands in the TOP lane of each octet ((lane&7)==7).
__device__ __forceinline__ float octet_sum(float x) {
    x = dpp_add<0x111>(x);
    x = dpp_add<0x112>(x);
    x = dpp_add<0x114>(x);
    return x;
}

// Octet BUTTERFLY sum over consecutive 8-lane groups: xor1, xor2, xor7
// (row_half_mirror). Result lands in ALL 8 lanes of each octet.
__device__ __forceinline__ float octet_bfly(float x) {
    x = dpp_add<0xB1>(x);    // quad_perm [1,0,3,2]  = xor 1
    x = dpp_add<0x4E>(x);    // quad_perm [2,3,0,1]  = xor 2
    x = dpp_add<0x141>(x);   // row_half_mirror       = xor 7 (completes octet)
    return x;
}

// ---------------------------------------------------------------------------
// Buffer resource descriptor (SRD) for bounds-checked MUBUF stores.
// ---------------------------------------------------------------------------
typedef __attribute__((ext_vector_type(4))) unsigned int srd_t;

__device__ __forceinline__ srd_t make_srd(const void* p, unsigned bytes) {
    const unsigned long long a = (unsigned long long)p;
    srd_t r;
    r.x = (unsigned)a;
    r.y = (unsigned)(a >> 32);     // stride bits [29:16] = 0
    r.z = bytes;                   // num_records (bytes, stride==0)
    r.w = 0x00020000u;             // raw untyped dword access
    return r;
}

// ---------------------------------------------------------------------------
// Async global->LDS copies (no VGPR destination). Tracked by vmcnt.
// ---------------------------------------------------------------------------
typedef __attribute__((address_space(1))) const void gas1_void;
typedef __attribute__((address_space(3))) void las3_void;
typedef __attribute__((address_space(3))) float las3_float;

__device__ __forceinline__ void gl_lds16(const float* g, float* l) {
    __builtin_amdgcn_global_load_lds((gas1_void*)g, (las3_void*)l, 16, 0, 0);
}
__device__ __forceinline__ void gl_lds4(const float* g, float* l) {
    __builtin_amdgcn_global_load_lds((gas1_void*)g, (las3_void*)l, 4, 0, 0);
}
// LDS byte offset of a __shared__ float* (AS3 pointer value == ds address).
__device__ __forceinline__ unsigned lds_off(float* p) {
    return (unsigned)(unsigned long long)(las3_float*)p;
}

// ---------------------------------------------------------------------------
// buildW: fold W_site with (sum_p ·) and with W_bridge; append W_gate.
//   Wcomb[d][f], f in [0,1024):    WA_perm  (scan-interleaved Abar columns)
//   f in [1024,2048):              WW[l*32+j] = sum_pr Ws[d,l*128+pr]*Wb[pr,j]
//   f in [2048,2560):              W_gate[d][f-2048]
// Block 512 == bias block (same folds applied to b_site / b_gate).
// Interleave map: f = 256q+4i+e  ->  l = 4*(i&7)+e,  r = (i>>3)+8q.
// ---------------------------------------------------------------------------
__global__ __launch_bounds__(256) void buildW_kernel(
    const float* __restrict__ Ws, const float* __restrict__ bs,
    const float* __restrict__ Wb, const float* __restrict__ Wg,
    const float* __restrict__ bg, float* __restrict__ Wcomb,
    float* __restrict__ biasC)
{
    const int tid = threadIdx.x;

    if (blockIdx.x == 512) {   // bias block
        for (int f = tid; f < NC_; f += 256) {
            float acc;
            if (f < 1024) {
                const int q = f >> 8, rem = f & 255, i = rem >> 2, e = rem & 3;
                const int l = 4 * (i & 7) + e, r = (i >> 3) + 8 * q;
                const float* p = bs + l * 128 + r;
                acc = p[0] + p[32] + p[64] + p[96];
            } else if (f < 2048) {
                const int g = f - 1024, l = g >> 5, j = g & 31;
                acc = 0.f;
                for (int pr = 0; pr < 128; ++pr)
                    acc = fmaf(bs[l * 128 + pr], Wb[pr * 32 + j], acc);
            } else {
                acc = bg[f - 2048];
            }
            biasC[f] = acc;
        }
        return;
    }

    __shared__ float wsrow[4096];
    __shared__ float wbs[4096];    // Wb[pr][j], pr*32+j

    const int d = blockIdx.x;
    #pragma unroll
    for (int i = 0; i < 16; ++i) {
        wsrow[i * 256 + tid] = Ws[(size_t)d * 4096 + i * 256 + tid];
        wbs[i * 256 + tid]   = Wb[i * 256 + tid];
    }
    __syncthreads();

    float* wrow = Wcomb + (size_t)d * NC_;

    // WA (interleaved): 4 cols/thread
    #pragma unroll
    for (int ii = 0; ii < 4; ++ii) {
        const int f = ii * 256 + tid;
        const int q = f >> 8, rem = f & 255, i = rem >> 2, e = rem & 3;
        const int l = 4 * (i & 7) + e, r = (i >> 3) + 8 * q;
        const float* p = wsrow + l * 128 + r;
        wrow[f] = p[0] + p[32] + p[64] + p[96];
    }
    // WW: 4 cols/thread, 128 FMA each
    #pragma unroll
    for (int ii = 0; ii < 4; ++ii) {
        const int g = ii * 256 + tid;
        const int l = g >> 5, j = g & 31;
        float acc = 0.f;
        #pragma unroll 8
        for (int pr = 0; pr < 128; ++pr)
            acc = fmaf(wsrow[l * 128 + pr], wbs[pr * 32 + j], acc);
        wrow[1024 + g] = acc;
    }
    // gate copy: 2 cols/thread
    #pragma unroll
    for (int ii = 0; ii < 2; ++ii) {
        const int c = ii * 256 + tid;
        wrow[2048 + c] = Wg[(size_t)d * 512 + c];
    }
}

// ---------------------------------------------------------------------------
// Generic fp32 GEMM with bias: C[M,N] = A[M,K] @ B[K,N] + bias[N]
// ---------------------------------------------------------------------------
__global__ __launch_bounds__(256) void gemm_bias_kernel(
    const float* __restrict__ A, const float* __restrict__ Bm,
    const float* __restrict__ bias, float* __restrict__ C,
    int M, int N, int K)
{
    __shared__ float As[32][68];
    __shared__ float Bs[32][64];

    const int tid = threadIdx.x;
    const int tx = tid & 15;
    const int ty = tid >> 4;
    const int m0 = blockIdx.y * 64;
    const int n0 = blockIdx.x * 64;

    float c[4][4] = {};

    for (int k0 = 0; k0 < K; k0 += 32) {
        {
            const int o = tid * 8;
            const int m = o >> 5;
            const int k = o & 31;
            const float* ap = A + (size_t)(m0 + m) * K + k0 + k;
            const float4 a0 = *(const float4*)ap;
            const float4 a1 = *(const float4*)(ap + 4);
            As[k + 0][m] = a0.x; As[k + 1][m] = a0.y;
            As[k + 2][m] = a0.z; As[k + 3][m] = a0.w;
            As[k + 4][m] = a1.x; As[k + 5][m] = a1.y;
            As[k + 6][m] = a1.z; As[k + 7][m] = a1.w;
        }
        {
            const int o = tid * 8;
            const int k = o >> 6;
            const int n = o & 63;
            const float* bp = Bm + (size_t)(k0 + k) * N + n0 + n;
            *(float4*)&Bs[k][n]     = *(const float4*)bp;
            *(float4*)&Bs[k][n + 4] = *(const float4*)(bp + 4);
        }
        __syncthreads();

        #pragma unroll
        for (int kk = 0; kk < 32; ++kk) {
            const float4 av = *(const float4*)&As[kk][ty * 4];
            const float4 bv = *(const float4*)&Bs[kk][tx * 4];
            const float a[4] = {av.x, av.y, av.z, av.w};
            const float b[4] = {bv.x, bv.y, bv.z, bv.w};
            #pragma unroll
            for (int i = 0; i < 4; ++i)
                #pragma unroll
                for (int j = 0; j < 4; ++j)
                    c[i][j] = fmaf(a[i], b[j], c[i][j]);
        }
        __syncthreads();
    }

    const float4 bv = *(const float4*)&bias[n0 + tx * 4];
    #pragma unroll
    for (int i = 0; i < 4; ++i) {
        float4 outv;
        outv.x = c[i][0] + bv.x;
        outv.y = c[i][1] + bv.y;
        outv.z = c[i][2] + bv.z;
        outv.w = c[i][3] + bv.w;
        *(float4*)&C[(size_t)(m0 + ty * 4 + i) * N + n0 + tx * 4] = outv;
    }
}

// ---------------------------------------------------------------------------
// cvec: c[bt][r] = sum_l u[l]*Abar[l][r], u = x[bt,0:32]. AbarI is the
// interleaved block at C[bt*NC_ + 0..1024). One wave per bt.
// ---------------------------------------------------------------------------
__global__ __launch_bounds__(256) void cvec_kernel(
    const float* __restrict__ Cc, const float* __restrict__ x,
    float* __restrict__ cBuf)
{
    const int tid  = threadIdx.x;
    const int lane = tid & 63;
    const int bt   = blockIdx.x * 4 + (tid >> 6);

    const float* base = Cc + (size_t)bt * NC_ + 4 * lane;
    float4 a0 = *(const float4*)(base + 0);
    float4 a1 = *(const float4*)(base + 256);
    float4 a2 = *(const float4*)(base + 512);
    float4 a3 = *(const float4*)(base + 768);

    const float u = x[(size_t)bt * D_ + (lane & 31)];
    const int idx0 = 16 * (lane & 7);
    const float u0 = bpermute_f(idx0 + 0,  u);
    const float u1 = bpermute_f(idx0 + 4,  u);
    const float u2 = bpermute_f(idx0 + 8,  u);
    const float u3 = bpermute_f(idx0 + 12, u);

    float p0 = fmaf(u3, a0.w, fmaf(u2, a0.z, fmaf(u1, a0.y, u0 * a0.x)));
    float p1 = fmaf(u3, a1.w, fmaf(u2, a1.z, fmaf(u1, a1.y, u0 * a1.x)));
    float p2 = fmaf(u3, a2.w, fmaf(u2, a2.z, fmaf(u1, a2.y, u0 * a2.x)));
    float p3 = fmaf(u3, a3.w, fmaf(u2, a3.z, fmaf(u1, a3.y, u0 * a3.x)));

    p0 = octet_sum(p0); p1 = octet_sum(p1);
    p2 = octet_sum(p2); p3 = octet_sum(p3);

    if ((lane & 7) == 7) {          // top lane of octet k holds m[k+8q]
        const int k = lane >> 3;
        float* cp = cBuf + (size_t)bt * 32 + k;
        cp[0]  = p0;
        cp[8]  = p1;
        cp[16] = p2;
        cp[24] = p3;
    }
}

// ---------------------------------------------------------------------------
// Serial scan, broadcast-layout state + LDS prefetch ring.
//
// State: lane (h = tid&7) holds wb_i = w[4h+i]. Per step:
//   nn = octet_bfly(sum wb^2); p_q partials; octet_bfly(p_q) -> m[k+8q];
//   pack rp = p_{tid&3}; one bpermute round gathers m[4h+i];
//   wb_i <- m_i*rsqrt(nn+eps) + c_i. Normalized h_t stored via asm SRD store.
//
// Prefetch: 16-slot LDS ring filled DPRE=8 steps ahead via global_load_lds
// (5 vmem issues/step). Slot consumption is a SINGLE inline-asm block of
// 5x ds_read_b128 ending with s_waitcnt lgkmcnt(0): the compiler sees no
// C++ LDS read, so the memory legalizer cannot inject its own vmcnt(0)
// drain (the round-5 2x regression); outputs are defined only when the
// whole asm retires, so there is no async-register hazard window.
//
// vmcnt FIFO (per step, chronological: [5 loads][wait][ds_read][2 stores]):
//   peel step J:  issued 40 + 7J + 5; need prologue slot-J loads (5(J+1))
//                 -> wait vmcnt(40+2J), J=0..7
//   steady step T: need step T-8's loads (fill slot T) -> newest allowed =
//                 2 (T-8 stores) + 49 (T-7..T-1) + 5 (T loads) = vmcnt(56)
// sched_barrier(0) pins [stores]->[next issue]->[wait] so counts are exact.
// Tail issues (t_is > 1023) read a few rows past the region (inside d_ws;
// never consumed).
// ---------------------------------------------------------------------------
#define SCAN_STEP(TT, W)                                                        \
    do {                                                                        \
        __builtin_amdgcn_sched_barrier(0);                                      \
        const int t_is = (TT) + DPRE;                                           \
        {                                                                       \
            float* sl = ldsb + (t_is & (SLOTS - 1)) * SLOT_F;                   \
            const float* ar = Abase + (size_t)t_is * NC_ + 4 * tid;             \
            gl_lds16(ar,       sl);                                             \
            gl_lds16(ar + 256, sl + 256);                                       \
            gl_lds16(ar + 512, sl + 512);                                       \
            gl_lds16(ar + 768, sl + 768);                                       \
            gl_lds4(cbase + (size_t)t_is * 32 + tid, sl + 1024);                \
        }                                                                       \
        __builtin_amdgcn_sched_barrier(0);                                      \
        asm volatile("s_waitcnt vmcnt(" W ")");                                 \
        __builtin_amdgcn_sched_barrier(0);                                      \
        float4 a0, a1, a2, a3, cv;                                              \
        {                                                                       \
            const unsigned sb = ldsbase                                         \
                + (unsigned)(((TT) & (SLOTS - 1)) * (SLOT_F * 4));              \
            const unsigned ab = sb + 16u * (unsigned)tid;                       \
            const unsigned cb = sb + 4096u + 16u * (unsigned)h;                 \
            asm volatile(                                                       \
                "ds_read_b128 %0, %5\n\t"                                       \
                "ds_read_b128 %1, %5 offset:1024\n\t"                           \
                "ds_read_b128 %2, %5 offset:2048\n\t"                           \
                "ds_read_b128 %3, %5 offset:3072\n\t"                           \
                "ds_read_b128 %4, %6\n\t"                                       \
                "s_waitcnt lgkmcnt(0)"                                          \
                : "=&v"(a0), "=&v"(a1), "=&v"(a2), "=&v"(a3), "=&v"(cv)         \
                : "v"(ab), "v"(cb));                                            \
        }                                                                       \
        float nn = fmaf(wb1, wb1, wb0 * wb0)                                    \
                 + fmaf(wb3, wb3, wb2 * wb2);                                   \
        nn = octet_bfly(nn);                                                    \
        const float rn = rsqrtf(nn + 1e-24f);                                   \
        float p0 = fmaf(wb1, a0.y, wb0 * a0.x) + fmaf(wb3, a0.w, wb2 * a0.z);   \
        float p1 = fmaf(wb1, a1.y, wb0 * a1.x) + fmaf(wb3, a1.w, wb2 * a1.z);   \
        float p2 = fmaf(wb1, a2.y, wb0 * a2.x) + fmaf(wb3, a2.w, wb2 * a2.z);   \
        float p3 = fmaf(wb1, a3.y, wb0 * a3.x) + fmaf(wb3, a3.w, wb2 * a3.z);   \
        p0 = octet_bfly(p0);                                                    \
        p1 = octet_bfly(p1);                                                    \
        p2 = octet_bfly(p2);                                                    \
        p3 = octet_bfly(p3);                                                    \
        const float rp = (tid & 2) ? ((tid & 1) ? p3 : p2)                      \
                                   : ((tid & 1) ? p1 : p0);                     \
        const float m0 = bpermute_f(idx0,      rp);                             \
        const float m1 = bpermute_f(idx0 + 32, rp);                             \
        const float m2 = bpermute_f(idx0 + 64, rp);                             \
        const float m3 = bpermute_f(idx0 + 96, rp);                             \
        const unsigned long long s01 =                                          \
            ((unsigned long long)__float_as_uint(wb1 * rn) << 32) |             \
            (unsigned)__float_as_uint(wb0 * rn);                                \
        const unsigned long long s23 =                                          \
            ((unsigned long long)__float_as_uint(wb3 * rn) << 32) |             \
            (unsigned)__float_as_uint(wb2 * rn);                                \
        asm volatile("buffer_store_dwordx2 %1, %0, %2, 0 offen"                 \
                     :: "v"(voffW), "v"(s01), "s"(srdW));                       \
        asm volatile("buffer_store_dwordx2 %1, %0, %2, 0 offen offset:8"        \
                     :: "v"(voffW), "v"(s23), "s"(srdW));                       \
        voffW += 128u;                                                          \
        wb0 = fmaf(m0, rn, cv.x);                                               \
        wb1 = fmaf(m1, rn, cv.y);                                               \
        wb2 = fmaf(m2, rn, cv.z);                                               \
        wb3 = fmaf(m3, rn, cv.w);                                               \
    } while (0)

__global__ __launch_bounds__(64, 1) void scan_kernel(
    const float* __restrict__ Cc, const float* __restrict__ cBuf,
    float* __restrict__ hnOut)
{
    __shared__ __align__(16) float ldsb[SLOTS * SLOT_F];   // 69,632 B

    const int b   = blockIdx.x;
    const int tid = threadIdx.x;            // 0..63
    const int h   = tid & 7;

    const float* Abase = Cc   + (size_t)b * L_ * NC_;
    const float* cbase = cBuf + (size_t)b * L_ * 32;
    const srd_t  srdW  = make_srd(hnOut + (size_t)b * L_ * 32,
                                  (unsigned)(L_ * 32 * 4));
    const unsigned ldsbase = lds_off(ldsb);

    // bpermute byte index: m[4h+i] lives at source lane 32*(h&1)+8*i+(h>>1)
    const int idx0 = 4 * (32 * (h & 1) + (h >> 1));

    unsigned voffW = (unsigned)(h * 16);

    // prologue: fill slots 0..7 (40 vmem ops)
    #pragma unroll
    for (int j = 0; j < DPRE; ++j) {
        float* sl = ldsb + j * SLOT_F;
        const float* ar = Abase + (size_t)j * NC_ + 4 * tid;
        gl_lds16(ar,       sl);
        gl_lds16(ar + 256, sl + 256);
        gl_lds16(ar + 512, sl + 512);
        gl_lds16(ar + 768, sl + 768);
        gl_lds4(cbase + (size_t)j * 32 + tid, sl + 1024);
    }

    float wb0 = 0.f, wb1 = 0.f, wb2 = 0.f, wb3 = 0.f;   // w_0 = 0

    // peeled first 8 steps (prologue-exact waits: 40+2J)
    SCAN_STEP(0, "40");
    SCAN_STEP(1, "42");
    SCAN_STEP(2, "44");
    SCAN_STEP(3, "46");
    SCAN_STEP(4, "48");
    SCAN_STEP(5, "50");
    SCAN_STEP(6, "52");
    SCAN_STEP(7, "54");

    for (int t = DPRE; t < L_; t += DPRE) {
        SCAN_STEP(t + 0, "56");
        SCAN_STEP(t + 1, "56");
        SCAN_STEP(t + 2, "56");
        SCAN_STEP(t + 3, "56");
        SCAN_STEP(t + 4, "56");
        SCAN_STEP(t + 5, "56");
        SCAN_STEP(t + 6, "56");
        SCAN_STEP(t + 7, "56");
    }
    asm volatile("s_waitcnt vmcnt(0)");
}
#undef SCAN_STEP

// ---------------------------------------------------------------------------
// Phase B: left = hn + u (hn already normalized by the scan);
// y1[j] = sum_l left[l]*G[l*32+j] + bb[j], G = C[bt*NC_ + 1024..2048).
// ---------------------------------------------------------------------------
__global__ __launch_bounds__(128) void phaseB_kernel(
    const float* __restrict__ Cc, const float* __restrict__ x,
    const float* __restrict__ hnBuf, const float* __restrict__ bb,
    float* __restrict__ y1)
{
    __shared__ float lf[32];
    __shared__ float part[4][32];

    const int bt = blockIdx.x;
    const int tid = threadIdx.x;

    if (tid < 32)
        lf[tid] = hnBuf[(size_t)bt * 32 + tid] + x[(size_t)bt * D_ + tid];
    __syncthreads();

    const int j = tid & 31, q = tid >> 5;
    const float* Gp = Cc + (size_t)bt * NC_ + 1024;
    float p = 0.f;
    #pragma unroll
    for (int i = 0; i < 8; ++i)
        p = fmaf(lf[8 * q + i], Gp[(8 * q + i) * 32 + j], p);
    part[q][j] = p;
    __syncthreads();

    if (tid < 32)
        y1[bt * 32 + tid] = part[0][tid] + part[1][tid] + part[2][tid]
                          + part[3][tid] + bb[tid];
}

// ---------------------------------------------------------------------------
// Epilogue: y = y1 @ W_out + b_out; LayerNorm; gated residual with x.
// gate logits live in C[bt*NC_ + 2048 ..2560).
// ---------------------------------------------------------------------------
__global__ __launch_bounds__(256) void epilogue_kernel(
    const float* __restrict__ x, const float* __restrict__ y1buf,
    const float* __restrict__ Wout, const float* __restrict__ bout,
    const float* __restrict__ gamma, const float* __restrict__ beta,
    const float* __restrict__ Cc, float* __restrict__ out)
{
    __shared__ float ys[32];
    __shared__ float red1[4], red2[4];

    const int bt = blockIdx.x;
    const int tid = threadIdx.x;

    if (tid < 32) ys[tid] = y1buf[bt * 32 + tid];
    __syncthreads();

    float yv[2];
    #pragma unroll
    for (int q = 0; q < 2; ++q) {
        const int d = tid + q * 256;
        float acc = bout[d];
        #pragma unroll
        for (int j = 0; j < 32; ++j)
            acc = fmaf(ys[j], Wout[j * D_ + d], acc);
        yv[q] = acc;
    }

    float s1 = yv[0] + yv[1];
    float s2 = yv[0] * yv[0] + yv[1] * yv[1];
    #pragma unroll
    for (int m = 1; m <= 32; m <<= 1) {
        s1 += __shfl_xor(s1, m);
        s2 += __shfl_xor(s2, m);
    }
    const int wid = tid >> 6;
    if ((tid & 63) == 0) { red1[wid] = s1; red2[wid] = s2; }
    __syncthreads();
    const float S1 = red1[0] + red1[1] + red1[2] + red1[3];
    const float S2 = red2[0] + red2[1] + red2[2] + red2[3];
    const float mu  = S1 * (1.f / (float)D_);
    const float var = S2 * (1.f / (float)D_) - mu * mu;
    const float rstd = rsqrtf(var + 1e-6f);

    #pragma unroll
    for (int q = 0; q < 2; ++q) {
        const int d = tid + q * 256;
        const size_t gi = (size_t)bt * D_ + d;
        const float yn = (yv[q] - mu) * rstd * gamma[d] + beta[d];
        const float z = Cc[(size_t)bt * NC_ + 2048 + d];
        const float g = 1.f / (1.f + expf(-z));
        const float xv = x[gi];
        out[gi] = g * yn + (1.f - g) * xv;
    }
}

// ---------------------------------------------------------------------------
extern "C" void kernel_launch(void* const* d_in, const int* in_sizes, int n_in,
                              void* d_out, int out_size, void* d_ws, size_t ws_size,
                              hipStream_t stream)
{
    const float* x        = (const float*)d_in[0];
    const float* W_site   = (const float*)d_in[1];
    const float* b_site   = (const float*)d_in[2];
    const float* W_bridge = (const float*)d_in[3];
    const float* b_bridge = (const float*)d_in[4];
    const float* W_out    = (const float*)d_in[5];
    const float* b_out    = (const float*)d_in[6];
    const float* gamma    = (const float*)d_in[7];
    const float* beta     = (const float*)d_in[8];
    const float* W_gate   = (const float*)d_in[9];
    const float* b_gate   = (const float*)d_in[10];
    float* out = (float*)d_out;

    float* ws = (float*)d_ws;
    float* Wcomb = ws;                            //   512*2560 = 1,310,720 f
    float* biasC = Wcomb + (size_t)512 * NC_;     //        2,560 f
    float* Cc    = biasC + NC_;                   // 4096*2560 = 10,485,760 f (42 MB)
    float* cBuf  = Cc    + (size_t)BT_ * NC_;     //      131,072 f
    float* hnBuf = cBuf  + (size_t)BT_ * 32;      //      131,072 f (normalized h_t)
    float* y1    = hnBuf + (size_t)BT_ * 32;      //      131,072 f

    // 0. fold weights: [WA_perm | WW | W_gate] + fused bias
    buildW_kernel<<<dim3(513), dim3(256), 0, stream>>>(
        W_site, b_site, W_bridge, W_gate, b_gate, Wcomb, biasC);

    // 1. one fused GEMM: C = x @ Wcomb + biasC   [4096 x 2560, K=512]
    gemm_bias_kernel<<<dim3(NC_ / 64, BT_ / 64), dim3(256), 0, stream>>>(
        x, Wcomb, biasC, Cc, BT_, NC_, D_);

    // 2. c vectors: c = u . Abar  (fully parallel)
    cvec_kernel<<<dim3(BT_ / 4), dim3(256), 0, stream>>>(Cc, x, cBuf);

    // 3. serial scan (4 waves total) -> normalized h_t
    scan_kernel<<<dim3(B_), dim3(64), 0, stream>>>(Cc, cBuf, hnBuf);

    // 4. phase B: y1 = (hn + u) . G + bb
    phaseB_kernel<<<dim3(BT_), dim3(128), 0, stream>>>(
        Cc, x, hnBuf, b_bridge, y1);

    // 5. epilogue: out-proj + LN + gated residual (gate from C)
    epilogue_kernel<<<dim3(BT_), dim3(256), 0, stream>>>(
        x, y1, W_out, b_out, gamma, beta, Cc, out);
}

// Round 8
// 454.976 us; speedup vs baseline: 1.4111x; 1.1087x over previous
//
#include <hip/hip_runtime.h>
#include <math.h>

// Problem dims (fixed by reference)
#define B_   4
#define L_   1024
#define D_   512
#define CHI_ 32
#define S_   4
#define BT_  (B_ * L_)          // 4096 rows
#define NC_  2560               // fused GEMM width: 1024 AbarI | 1024 G | 512 gate
#define DPRE 8                  // scan prefetch distance (register ring)

// ---------------------------------------------------------------------------
// Cross-lane helpers
// ---------------------------------------------------------------------------
__device__ __forceinline__ float readlane_f(float v, int l) {
    return __int_as_float(__builtin_amdgcn_readlane(__float_as_int(v), l));
}

__device__ __forceinline__ float bpermute_f(int byte_idx, float v) {
    return __int_as_float(__builtin_amdgcn_ds_bpermute(byte_idx, __float_as_int(v)));
}

template <int CTRL>
__device__ __forceinline__ float dpp_add(float x) {
    int y = __builtin_amdgcn_update_dpp(0, __float_as_int(x), CTRL, 0xf, 0xf, true);
    return x + __int_as_float(y);
}

// Sum of lanes 0..31, valid in lane 31 (row_shr moves toward HIGHER lanes).
__device__ __forceinline__ float reduce32_to_lane31(float x) {
    x = dpp_add<0x111>(x);
    x = dpp_add<0x112>(x);
    x = dpp_add<0x114>(x);
    x = dpp_add<0x118>(x);
    x = dpp_add<0x142>(x);  // row_bcast15 -> lane31
    return x;
}

// Octet sum; complete sum lands in the TOP lane of each octet ((lane&7)==7).
__device__ __forceinline__ float octet_sum(float x) {
    x = dpp_add<0x111>(x);
    x = dpp_add<0x112>(x);
    x = dpp_add<0x114>(x);
    return x;
}

// ---------------------------------------------------------------------------
// buildW: fold W_site with (sum_p ·) and with W_bridge; append W_gate.
//   Wcomb[d][f], f in [0,1024):    WA_perm  (scan-interleaved Abar columns)
//   f in [1024,2048):              WW[l*32+j] = sum_pr Ws[d,l*128+pr]*Wb[pr,j]
//   f in [2048,2560):              W_gate[d][f-2048]
// Block 512 == bias block (same folds applied to b_site / b_gate).
// Interleave map: f = 256q+4i+e  ->  l = 4*(i&7)+e,  r = (i>>3)+8q.
// ---------------------------------------------------------------------------
__global__ __launch_bounds__(256) void buildW_kernel(
    const float* __restrict__ Ws, const float* __restrict__ bs,
    const float* __restrict__ Wb, const float* __restrict__ Wg,
    const float* __restrict__ bg, float* __restrict__ Wcomb,
    float* __restrict__ biasC)
{
    const int tid = threadIdx.x;

    if (blockIdx.x == 512) {   // bias block
        for (int f = tid; f < NC_; f += 256) {
            float acc;
            if (f < 1024) {
                const int q = f >> 8, rem = f & 255, i = rem >> 2, e = rem & 3;
                const int l = 4 * (i & 7) + e, r = (i >> 3) + 8 * q;
                const float* p = bs + l * 128 + r;
                acc = p[0] + p[32] + p[64] + p[96];
            } else if (f < 2048) {
                const int g = f - 1024, l = g >> 5, j = g & 31;
                acc = 0.f;
                for (int pr = 0; pr < 128; ++pr)
                    acc = fmaf(bs[l * 128 + pr], Wb[pr * 32 + j], acc);
            } else {
                acc = bg[f - 2048];
            }
            biasC[f] = acc;
        }
        return;
    }

    __shared__ float wsrow[4096];
    __shared__ float wbs[4096];    // Wb[pr][j], pr*32+j

    const int d = blockIdx.x;
    #pragma unroll
    for (int i = 0; i < 16; ++i) {
        wsrow[i * 256 + tid] = Ws[(size_t)d * 4096 + i * 256 + tid];
        wbs[i * 256 + tid]   = Wb[i * 256 + tid];
    }
    __syncthreads();

    float* wrow = Wcomb + (size_t)d * NC_;

    // WA (interleaved): 4 cols/thread
    #pragma unroll
    for (int ii = 0; ii < 4; ++ii) {
        const int f = ii * 256 + tid;
        const int q = f >> 8, rem = f & 255, i = rem >> 2, e = rem & 3;
        const int l = 4 * (i & 7) + e, r = (i >> 3) + 8 * q;
        const float* p = wsrow + l * 128 + r;
        wrow[f] = p[0] + p[32] + p[64] + p[96];
    }
    // WW: 4 cols/thread, 128 FMA each
    #pragma unroll
    for (int ii = 0; ii < 4; ++ii) {
        const int g = ii * 256 + tid;
        const int l = g >> 5, j = g & 31;
        float acc = 0.f;
        #pragma unroll 8
        for (int pr = 0; pr < 128; ++pr)
            acc = fmaf(wsrow[l * 128 + pr], wbs[pr * 32 + j], acc);
        wrow[1024 + g] = acc;
    }
    // gate copy: 2 cols/thread
    #pragma unroll
    for (int ii = 0; ii < 2; ++ii) {
        const int c = ii * 256 + tid;
        wrow[2048 + c] = Wg[(size_t)d * 512 + c];
    }
}

// ---------------------------------------------------------------------------
// fp32 GEMM with bias: C[M,N] = A[M,K] @ B[K,N] + bias[N]
// 128x128 tile, 256 threads, 8x8 acc/thread, BK=32 (single-buffer LDS).
// As is stored transposed [k][m] (pad 132 -> 16B-aligned rows, float4 reads).
// ---------------------------------------------------------------------------
__global__ __launch_bounds__(256) void gemm_bias_kernel(
    const float* __restrict__ A, const float* __restrict__ Bm,
    const float* __restrict__ bias, float* __restrict__ C,
    int M, int N, int K)
{
    __shared__ float As[32][132];   // As[k][m]
    __shared__ float Bs[32][132];   // Bs[k][n]

    const int tid = threadIdx.x;
    const int tx = tid & 15;        // col group (n)
    const int ty = tid >> 4;        // row group (m)
    const int m0 = blockIdx.y * 128;
    const int n0 = blockIdx.x * 128;

    float acc[8][8] = {};

    for (int k0 = 0; k0 < K; k0 += 32) {
        // A tile: 128 rows x 32 k, write transposed As[k][m]
        #pragma unroll
        for (int p = 0; p < 4; ++p) {
            const int m = (tid >> 3) + 32 * p;
            const int k = (tid & 7) * 4;
            const float4 av = *(const float4*)(A + (size_t)(m0 + m) * K + k0 + k);
            As[k + 0][m] = av.x;
            As[k + 1][m] = av.y;
            As[k + 2][m] = av.z;
            As[k + 3][m] = av.w;
        }
        // B tile: 32 k x 128 n
        #pragma unroll
        for (int p = 0; p < 2; ++p) {
            const int k = (tid >> 4) + 16 * p;
            const int n = (tid & 15) * 8;
            const float* bp = Bm + (size_t)(k0 + k) * N + n0 + n;
            *(float4*)&Bs[k][n]     = *(const float4*)bp;
            *(float4*)&Bs[k][n + 4] = *(const float4*)(bp + 4);
        }
        __syncthreads();

        #pragma unroll
        for (int kk = 0; kk < 32; ++kk) {
            const float4 a0 = *(const float4*)&As[kk][ty * 8];
            const float4 a1 = *(const float4*)&As[kk][ty * 8 + 4];
            const float4 b0 = *(const float4*)&Bs[kk][tx * 8];
            const float4 b1 = *(const float4*)&Bs[kk][tx * 8 + 4];
            const float a[8] = {a0.x, a0.y, a0.z, a0.w, a1.x, a1.y, a1.z, a1.w};
            const float b[8] = {b0.x, b0.y, b0.z, b0.w, b1.x, b1.y, b1.z, b1.w};
            #pragma unroll
            for (int i = 0; i < 8; ++i)
                #pragma unroll
                for (int j = 0; j < 8; ++j)
                    acc[i][j] = fmaf(a[i], b[j], acc[i][j]);
        }
        __syncthreads();
    }

    const float4 bv0 = *(const float4*)&bias[n0 + tx * 8];
    const float4 bv1 = *(const float4*)&bias[n0 + tx * 8 + 4];
    #pragma unroll
    for (int i = 0; i < 8; ++i) {
        float* cp = C + (size_t)(m0 + ty * 8 + i) * N + n0 + tx * 8;
        float4 o0, o1;
        o0.x = acc[i][0] + bv0.x; o0.y = acc[i][1] + bv0.y;
        o0.z = acc[i][2] + bv0.z; o0.w = acc[i][3] + bv0.w;
        o1.x = acc[i][4] + bv1.x; o1.y = acc[i][5] + bv1.y;
        o1.z = acc[i][6] + bv1.z; o1.w = acc[i][7] + bv1.w;
        *(float4*)cp       = o0;
        *(float4*)(cp + 4) = o1;
    }
}

// ---------------------------------------------------------------------------
// cvec: c[bt][r] = sum_l u[l]*Abar[l][r], u = x[bt,0:32]. AbarI is the
// interleaved block at C[bt*NC_ + 0..1024). Same bpermute/octet machinery as
// the scan, one wave per bt (4 bt per 256-thread block).
// ---------------------------------------------------------------------------
__global__ __launch_bounds__(256) void cvec_kernel(
    const float* __restrict__ Cc, const float* __restrict__ x,
    float* __restrict__ cBuf)
{
    const int tid  = threadIdx.x;
    const int lane = tid & 63;
    const int bt   = blockIdx.x * 4 + (tid >> 6);

    const float* base = Cc + (size_t)bt * NC_ + 4 * lane;
    float4 a0 = *(const float4*)(base + 0);
    float4 a1 = *(const float4*)(base + 256);
    float4 a2 = *(const float4*)(base + 512);
    float4 a3 = *(const float4*)(base + 768);

    const float u = x[(size_t)bt * D_ + (lane & 31)];
    const int idx0 = 16 * (lane & 7);
    const float u0 = bpermute_f(idx0 + 0,  u);
    const float u1 = bpermute_f(idx0 + 4,  u);
    const float u2 = bpermute_f(idx0 + 8,  u);
    const float u3 = bpermute_f(idx0 + 12, u);

    float p0 = fmaf(u3, a0.w, fmaf(u2, a0.z, fmaf(u1, a0.y, u0 * a0.x)));
    float p1 = fmaf(u3, a1.w, fmaf(u2, a1.z, fmaf(u1, a1.y, u0 * a1.x)));
    float p2 = fmaf(u3, a2.w, fmaf(u2, a2.z, fmaf(u1, a2.y, u0 * a2.x)));
    float p3 = fmaf(u3, a3.w, fmaf(u2, a3.z, fmaf(u1, a3.y, u0 * a3.x)));

    p0 = octet_sum(p0); p1 = octet_sum(p1);
    p2 = octet_sum(p2); p3 = octet_sum(p3);

    if ((lane & 7) == 7) {          // top lane of octet k holds m[k+8q]
        const int k = lane >> 3;
        float* cp = cBuf + (size_t)bt * 32 + k;
        cp[0]  = p0;
        cp[8]  = p1;
        cp[16] = p2;
        cp[24] = p3;
    }
}

// ---------------------------------------------------------------------------
// Serial scan, homogeneous form. One wave per batch.
//   w_{t+1} = (w_t . Abar_t) * rsqrt(sum w_t^2) + c_t
// AbarI rows live in C at row stride NC_ (first 1024 columns).
// ---------------------------------------------------------------------------
__global__ __launch_bounds__(64, 1) void scan_kernel(
    const float* __restrict__ Cc, const float* __restrict__ cBuf,
    float* __restrict__ wOut)
{
    const int b   = blockIdx.x;
    const int tid = threadIdx.x;

    const float* At = Cc + (size_t)b * L_ * NC_ + 4 * tid;   // lane base
    const float* cb = cBuf + (size_t)b * L_ * 32 + (tid & 31);
    float*       wo = wOut + (size_t)b * L_ * 64 + tid;

    const int idx0 = 16 * (tid & 7);
    const int idxR = 32 * (tid & 7) + 28;    // octet TOP lane
    const bool selA = (tid >> 3) & 1;
    const bool selB = (tid >> 4) & 1;

    float4 areg[DPRE][4];
    float  creg[DPRE];

    #pragma unroll
    for (int j = 0; j < DPRE; ++j) {
        const float* ap = At + (size_t)j * NC_;
        #pragma unroll
        for (int q = 0; q < 4; ++q) areg[j][q] = *(const float4*)(ap + 256 * q);
        creg[j] = cb[j * 32];
    }

    float w = 0.f;   // w_0 = 0  (h_0 = 0)

    for (int t = 0; t < L_; t += DPRE) {
        #pragma unroll
        for (int j = 0; j < DPRE; ++j) {
            wo[(t + j) * 64] = w;

            float red = reduce32_to_lane31(w * w);

            const float wb0 = bpermute_f(idx0 + 0,  w);
            const float wb1 = bpermute_f(idx0 + 4,  w);
            const float wb2 = bpermute_f(idx0 + 8,  w);
            const float wb3 = bpermute_f(idx0 + 12, w);

            float p0, p1, p2, p3;
            {
                const float4 a0 = areg[j][0], a1 = areg[j][1];
                const float4 a2 = areg[j][2], a3 = areg[j][3];
                p0 = fmaf(wb3, a0.w, fmaf(wb2, a0.z, fmaf(wb1, a0.y, wb0 * a0.x)));
                p1 = fmaf(wb3, a1.w, fmaf(wb2, a1.z, fmaf(wb1, a1.y, wb0 * a1.x)));
                p2 = fmaf(wb3, a2.w, fmaf(wb2, a2.z, fmaf(wb1, a2.y, wb0 * a2.x)));
                p3 = fmaf(wb3, a3.w, fmaf(wb2, a3.z, fmaf(wb1, a3.y, wb0 * a3.x)));
            }

            p0 = octet_sum(p0);
            p1 = octet_sum(p1);
            p2 = octet_sum(p2);
            p3 = octet_sum(p3);

            const float m0 = bpermute_f(idxR, p0);
            const float m1 = bpermute_f(idxR, p1);
            const float m2 = bpermute_f(idxR, p2);
            const float m3 = bpermute_f(idxR, p3);
            const float t0 = selA ? m1 : m0;
            const float t1 = selA ? m3 : m2;
            const float m  = selB ? t1 : t0;

            const float n2 = readlane_f(red, 31);
            const float rn = rsqrtf(n2 + 1e-24f);
            w = fmaf(m, rn, creg[j]);

            int tn = t + j + DPRE;
            if (tn > L_ - 1) tn = L_ - 1;
            const float* ap = At + (size_t)tn * NC_;
            #pragma unroll
            for (int q = 0; q < 4; ++q) areg[j][q] = *(const float4*)(ap + 256 * q);
            creg[j] = cb[tn * 32];
        }
    }
}

// ---------------------------------------------------------------------------
// Phase B: left = w/||w|| + u; y1[j] = sum_l left[l]*G[l*32+j] + bb[j],
// where G is C[bt*NC_ + 1024 ..2048).
// ---------------------------------------------------------------------------
__global__ __launch_bounds__(128) void phaseB_kernel(
    const float* __restrict__ Cc, const float* __restrict__ x,
    const float* __restrict__ wBuf, const float* __restrict__ bb,
    float* __restrict__ y1)
{
    __shared__ float lf[32];
    __shared__ float part[4][32];

    const int bt = blockIdx.x;
    const int tid = threadIdx.x;

    if (tid < 64) {
        const float wv = wBuf[(size_t)bt * 64 + tid];
        float red = reduce32_to_lane31(wv * wv);
        const float n2 = readlane_f(red, 31);
        const float rn = rsqrtf(n2 + 1e-24f);
        if (tid < 32)
            lf[tid] = fmaf(wv, rn, x[(size_t)bt * D_ + tid]);  // left = h + u
    }
    __syncthreads();

    const int j = tid & 31, q = tid >> 5;
    const float* Gp = Cc + (size_t)bt * NC_ + 1024;
    float p = 0.f;
    #pragma unroll
    for (int i = 0; i < 8; ++i)
        p = fmaf(lf[8 * q + i], Gp[(8 * q + i) * 32 + j], p);
    part[q][j] = p;
    __syncthreads();

    if (tid < 32)
        y1[bt * 32 + tid] = part[0][tid] + part[1][tid] + part[2][tid]
                          + part[3][tid] + bb[tid];
}

// ---------------------------------------------------------------------------
// Epilogue: y = y1 @ W_out + b_out; LayerNorm; gated residual with x.
// gate logits live in C[bt*NC_ + 2048 ..2560).
// ---------------------------------------------------------------------------
__global__ __launch_bounds__(256) void epilogue_kernel(
    const float* __restrict__ x, const float* __restrict__ y1buf,
    const float* __restrict__ Wout, const float* __restrict__ bout,
    const float* __restrict__ gamma, const float* __restrict__ beta,
    const float* __restrict__ Cc, float* __restrict__ out)
{
    __shared__ float ys[32];
    __shared__ float red1[4], red2[4];

    const int bt = blockIdx.x;
    const int tid = threadIdx.x;

    if (tid < 32) ys[tid] = y1buf[bt * 32 + tid];
    __syncthreads();

    float yv[2];
    #pragma unroll
    for (int q = 0; q < 2; ++q) {
        const int d = tid + q * 256;
        float acc = bout[d];
        #pragma unroll
        for (int j = 0; j < 32; ++j)
            acc = fmaf(ys[j], Wout[j * D_ + d], acc);
        yv[q] = acc;
    }

    float s1 = yv[0] + yv[1];
    float s2 = yv[0] * yv[0] + yv[1] * yv[1];
    #pragma unroll
    for (int m = 1; m <= 32; m <<= 1) {
        s1 += __shfl_xor(s1, m);
        s2 += __shfl_xor(s2, m);
    }
    const int wid = tid >> 6;
    if ((tid & 63) == 0) { red1[wid] = s1; red2[wid] = s2; }
    __syncthreads();
    const float S1 = red1[0] + red1[1] + red1[2] + red1[3];
    const float S2 = red2[0] + red2[1] + red2[2] + red2[3];
    const float mu  = S1 * (1.f / (float)D_);
    const float var = S2 * (1.f / (float)D_) - mu * mu;
    const float rstd = rsqrtf(var + 1e-6f);

    #pragma unroll
    for (int q = 0; q < 2; ++q) {
        const int d = tid + q * 256;
        const size_t gi = (size_t)bt * D_ + d;
        const float yn = (yv[q] - mu) * rstd * gamma[d] + beta[d];
        const float z = Cc[(size_t)bt * NC_ + 2048 + d];
        const float g = 1.f / (1.f + expf(-z));
        const float xv = x[gi];
        out[gi] = g * yn + (1.f - g) * xv;
    }
}

// ---------------------------------------------------------------------------
extern "C" void kernel_launch(void* const* d_in, const int* in_sizes, int n_in,
                              void* d_out, int out_size, void* d_ws, size_t ws_size,
                              hipStream_t stream)
{
    const float* x        = (const float*)d_in[0];
    const float* W_site   = (const float*)d_in[1];
    const float* b_site   = (const float*)d_in[2];
    const float* W_bridge = (const float*)d_in[3];
    const float* b_bridge = (const float*)d_in[4];
    const float* W_out    = (const float*)d_in[5];
    const float* b_out    = (const float*)d_in[6];
    const float* gamma    = (const float*)d_in[7];
    const float* beta     = (const float*)d_in[8];
    const float* W_gate   = (const float*)d_in[9];
    const float* b_gate   = (const float*)d_in[10];
    float* out = (float*)d_out;

    float* ws = (float*)d_ws;
    float* Wcomb = ws;                            //   512*2560 = 1,310,720 f
    float* biasC = Wcomb + (size_t)512 * NC_;     //        2,560 f
    float* Cc    = biasC + NC_;                   // 4096*2560 = 10,485,760 f (42 MB)
    float* cBuf  = Cc    + (size_t)BT_ * NC_;     //      131,072 f
    float* wBuf  = cBuf  + (size_t)BT_ * 32;      //      262,144 f
    float* y1    = wBuf  + (size_t)BT_ * 64;      //      131,072 f

    // 0. fold weights: [WA_perm | WW | W_gate] + fused bias
    buildW_kernel<<<dim3(513), dim3(256), 0, stream>>>(
        W_site, b_site, W_bridge, W_gate, b_gate, Wcomb, biasC);

    // 1. one fused GEMM: C = x @ Wcomb + biasC   [4096 x 2560, K=512]
    gemm_bias_kernel<<<dim3(NC_ / 128, BT_ / 128), dim3(256), 0, stream>>>(
        x, Wcomb, biasC, Cc, BT_, NC_, D_);

    // 2. c vectors: c = u . Abar  (fully parallel)
    cvec_kernel<<<dim3(BT_ / 4), dim3(256), 0, stream>>>(Cc, x, cBuf);

    // 3. serial scan (4 waves total) -> w_t
    scan_kernel<<<dim3(B_), dim3(64), 0, stream>>>(Cc, cBuf, wBuf);

    // 4. phase B: y1 = left . G + bb
    phaseB_kernel<<<dim3(BT_), dim3(128), 0, stream>>>(
        Cc, x, wBuf, b_bridge, y1);

    // 5. epilogue: out-proj + LN + gated residual (gate from C)
    epilogue_kernel<<<dim3(BT_), dim3(256), 0, stream>>>(
        x, y1, W_out, b_out, gamma, beta, Cc, out);
}

// Round 10
// 390.680 us; speedup vs baseline: 1.6434x; 1.1646x over previous
//
#include <hip/hip_runtime.h>
#include <math.h>

// Problem dims (fixed by reference)
#define B_   4
#define L_   1024
#define D_   512
#define CHI_ 32
#define S_   4
#define BT_  (B_ * L_)          // 4096 rows
#define NC_  2560               // fused GEMM width: 1024 AbarI | 1024 G | 512 gate
#define DPRE 8                  // scan prefetch distance (register ring)

// ---------------------------------------------------------------------------
// Cross-lane helpers
// ---------------------------------------------------------------------------
__device__ __forceinline__ float readlane_f(float v, int l) {
    return __int_as_float(__builtin_amdgcn_readlane(__float_as_int(v), l));
}

__device__ __forceinline__ float bpermute_f(int byte_idx, float v) {
    return __int_as_float(__builtin_amdgcn_ds_bpermute(byte_idx, __float_as_int(v)));
}

template <int CTRL>
__device__ __forceinline__ float dpp_add(float x) {
    int y = __builtin_amdgcn_update_dpp(0, __float_as_int(x), CTRL, 0xf, 0xf, true);
    return x + __int_as_float(y);
}

// Sum of lanes 0..31, valid in lane 31 (row_shr moves toward HIGHER lanes).
__device__ __forceinline__ float reduce32_to_lane31(float x) {
    x = dpp_add<0x111>(x);
    x = dpp_add<0x112>(x);
    x = dpp_add<0x114>(x);
    x = dpp_add<0x118>(x);
    x = dpp_add<0x142>(x);  // row_bcast15 -> lane31
    return x;
}

// Octet sum; complete sum lands in the TOP lane of each octet ((lane&7)==7).
__device__ __forceinline__ float octet_sum(float x) {
    x = dpp_add<0x111>(x);
    x = dpp_add<0x112>(x);
    x = dpp_add<0x114>(x);
    return x;
}

// ---------------------------------------------------------------------------
// buildW: fold W_site with (sum_p ·) and with W_bridge; append W_gate.
//   Wcomb[d][f], f in [0,1024):    WA_perm  (scan-interleaved Abar columns)
//   f in [1024,2048):              WW[l*32+j] = sum_pr Ws[d,l*128+pr]*Wb[pr,j]
//   f in [2048,2560):              W_gate[d][f-2048]
// Block 512 == bias block (same folds applied to b_site / b_gate).
// Interleave map: f = 256q+4i+e  ->  l = 4*(i&7)+e,  r = (i>>3)+8q.
// ---------------------------------------------------------------------------
__global__ __launch_bounds__(256) void buildW_kernel(
    const float* __restrict__ Ws, const float* __restrict__ bs,
    const float* __restrict__ Wb, const float* __restrict__ Wg,
    const float* __restrict__ bg, float* __restrict__ Wcomb,
    float* __restrict__ biasC)
{
    const int tid = threadIdx.x;

    if (blockIdx.x == 512) {   // bias block
        for (int f = tid; f < NC_; f += 256) {
            float acc;
            if (f < 1024) {
                const int q = f >> 8, rem = f & 255, i = rem >> 2, e = rem & 3;
                const int l = 4 * (i & 7) + e, r = (i >> 3) + 8 * q;
                const float* p = bs + l * 128 + r;
                acc = p[0] + p[32] + p[64] + p[96];
            } else if (f < 2048) {
                const int g = f - 1024, l = g >> 5, j = g & 31;
                acc = 0.f;
                for (int pr = 0; pr < 128; ++pr)
                    acc = fmaf(bs[l * 128 + pr], Wb[pr * 32 + j], acc);
            } else {
                acc = bg[f - 2048];
            }
            biasC[f] = acc;
        }
        return;
    }

    __shared__ float wsrow[4096];
    __shared__ float wbs[4096];    // Wb[pr][j], pr*32+j

    const int d = blockIdx.x;
    #pragma unroll
    for (int i = 0; i < 16; ++i) {
        wsrow[i * 256 + tid] = Ws[(size_t)d * 4096 + i * 256 + tid];
        wbs[i * 256 + tid]   = Wb[i * 256 + tid];
    }
    __syncthreads();

    float* wrow = Wcomb + (size_t)d * NC_;

    // WA (interleaved): 4 cols/thread
    #pragma unroll
    for (int ii = 0; ii < 4; ++ii) {
        const int f = ii * 256 + tid;
        const int q = f >> 8, rem = f & 255, i = rem >> 2, e = rem & 3;
        const int l = 4 * (i & 7) + e, r = (i >> 3) + 8 * q;
        const float* p = wsrow + l * 128 + r;
        wrow[f] = p[0] + p[32] + p[64] + p[96];
    }
    // WW: 4 cols/thread, 128 FMA each
    #pragma unroll
    for (int ii = 0; ii < 4; ++ii) {
        const int g = ii * 256 + tid;
        const int l = g >> 5, j = g & 31;
        float acc = 0.f;
        #pragma unroll 8
        for (int pr = 0; pr < 128; ++pr)
            acc = fmaf(wsrow[l * 128 + pr], wbs[pr * 32 + j], acc);
        wrow[1024 + g] = acc;
    }
    // gate copy: 2 cols/thread
    #pragma unroll
    for (int ii = 0; ii < 2; ++ii) {
        const int c = ii * 256 + tid;
        wrow[2048 + c] = Wg[(size_t)d * 512 + c];
    }
}

// ---------------------------------------------------------------------------
// GEMM tile body (shared by part-1 kernel and the fused kernel).
// 128x128 tile, 256 threads, 8x8 acc/thread, BK=32 (single-buffer LDS).
// As stored transposed [k][m] (pad 132 -> 16B-aligned rows, float4 reads).
// ---------------------------------------------------------------------------
__device__ __forceinline__ void gemm_tile_body(
    const float* __restrict__ A, const float* __restrict__ Bm,
    const float* __restrict__ bias, float* __restrict__ C,
    int M, int N, int K, int m0, int n0,
    float (*As)[132], float (*Bs)[132])
{
    const int tid = threadIdx.x;
    const int tx = tid & 15;        // col group (n)
    const int ty = tid >> 4;        // row group (m)

    float acc[8][8] = {};

    for (int k0 = 0; k0 < K; k0 += 32) {
        // A tile: 128 rows x 32 k, write transposed As[k][m]
        #pragma unroll
        for (int p = 0; p < 4; ++p) {
            const int m = (tid >> 3) + 32 * p;
            const int k = (tid & 7) * 4;
            const float4 av = *(const float4*)(A + (size_t)(m0 + m) * K + k0 + k);
            As[k + 0][m] = av.x;
            As[k + 1][m] = av.y;
            As[k + 2][m] = av.z;
            As[k + 3][m] = av.w;
        }
        // B tile: 32 k x 128 n
        #pragma unroll
        for (int p = 0; p < 2; ++p) {
            const int k = (tid >> 4) + 16 * p;
            const int n = (tid & 15) * 8;
            const float* bp = Bm + (size_t)(k0 + k) * N + n0 + n;
            *(float4*)&Bs[k][n]     = *(const float4*)bp;
            *(float4*)&Bs[k][n + 4] = *(const float4*)(bp + 4);
        }
        __syncthreads();

        #pragma unroll
        for (int kk = 0; kk < 32; ++kk) {
            const float4 a0 = *(const float4*)&As[kk][ty * 8];
            const float4 a1 = *(const float4*)&As[kk][ty * 8 + 4];
            const float4 b0 = *(const float4*)&Bs[kk][tx * 8];
            const float4 b1 = *(const float4*)&Bs[kk][tx * 8 + 4];
            const float a[8] = {a0.x, a0.y, a0.z, a0.w, a1.x, a1.y, a1.z, a1.w};
            const float b[8] = {b0.x, b0.y, b0.z, b0.w, b1.x, b1.y, b1.z, b1.w};
            #pragma unroll
            for (int i = 0; i < 8; ++i)
                #pragma unroll
                for (int j = 0; j < 8; ++j)
                    acc[i][j] = fmaf(a[i], b[j], acc[i][j]);
        }
        __syncthreads();
    }

    const float4 bv0 = *(const float4*)&bias[n0 + tx * 8];
    const float4 bv1 = *(const float4*)&bias[n0 + tx * 8 + 4];
    #pragma unroll
    for (int i = 0; i < 8; ++i) {
        float* cp = C + (size_t)(m0 + ty * 8 + i) * N + n0 + tx * 8;
        float4 o0, o1;
        o0.x = acc[i][0] + bv0.x; o0.y = acc[i][1] + bv0.y;
        o0.z = acc[i][2] + bv0.z; o0.w = acc[i][3] + bv0.w;
        o1.x = acc[i][4] + bv1.x; o1.y = acc[i][5] + bv1.y;
        o1.z = acc[i][6] + bv1.z; o1.w = acc[i][7] + bv1.w;
        *(float4*)cp       = o0;
        *(float4*)(cp + 4) = o1;
    }
}

// Part 1: C columns [0, 1024)  (AbarI block, needed by cvec + scan)
__global__ __launch_bounds__(256) void gemm_bias_kernel(
    const float* __restrict__ A, const float* __restrict__ Bm,
    const float* __restrict__ bias, float* __restrict__ C,
    int M, int N, int K)
{
    __shared__ float As[32][132];
    __shared__ float Bs[32][132];
    gemm_tile_body(A, Bm, bias, C, M, N, K,
                   blockIdx.y * 128, blockIdx.x * 128, As, Bs);
}

// ---------------------------------------------------------------------------
// cvec: c[bt][r] = sum_l u[l]*Abar[l][r], u = x[bt,0:32]. AbarI is the
// interleaved block at C[bt*NC_ + 0..1024). Same bpermute/octet machinery as
// the scan, one wave per bt (4 bt per 256-thread block).
// ---------------------------------------------------------------------------
__global__ __launch_bounds__(256) void cvec_kernel(
    const float* __restrict__ Cc, const float* __restrict__ x,
    float* __restrict__ cBuf)
{
    const int tid  = threadIdx.x;
    const int lane = tid & 63;
    const int bt   = blockIdx.x * 4 + (tid >> 6);

    const float* base = Cc + (size_t)bt * NC_ + 4 * lane;
    float4 a0 = *(const float4*)(base + 0);
    float4 a1 = *(const float4*)(base + 256);
    float4 a2 = *(const float4*)(base + 512);
    float4 a3 = *(const float4*)(base + 768);

    const float u = x[(size_t)bt * D_ + (lane & 31)];
    const int idx0 = 16 * (lane & 7);
    const float u0 = bpermute_f(idx0 + 0,  u);
    const float u1 = bpermute_f(idx0 + 4,  u);
    const float u2 = bpermute_f(idx0 + 8,  u);
    const float u3 = bpermute_f(idx0 + 12, u);

    float p0 = fmaf(u3, a0.w, fmaf(u2, a0.z, fmaf(u1, a0.y, u0 * a0.x)));
    float p1 = fmaf(u3, a1.w, fmaf(u2, a1.z, fmaf(u1, a1.y, u0 * a1.x)));
    float p2 = fmaf(u3, a2.w, fmaf(u2, a2.z, fmaf(u1, a2.y, u0 * a2.x)));
    float p3 = fmaf(u3, a3.w, fmaf(u2, a3.z, fmaf(u1, a3.y, u0 * a3.x)));

    p0 = octet_sum(p0); p1 = octet_sum(p1);
    p2 = octet_sum(p2); p3 = octet_sum(p3);

    if ((lane & 7) == 7) {          // top lane of octet k holds m[k+8q]
        const int k = lane >> 3;
        float* cp = cBuf + (size_t)bt * 32 + k;
        cp[0]  = p0;
        cp[8]  = p1;
        cp[16] = p2;
        cp[24] = p3;
    }
}

// ---------------------------------------------------------------------------
// FUSED: serial scan (blocks 0..3, tid<64) + GEMM part 2 (blocks 4..387,
// C columns [1024, 2560) = G + gate). The scan reads C cols [0,1024) and
// cBuf (both finalized by prior dispatches); the GEMM writes cols
// [1024,2560) -- fully disjoint, no inter-block dependency. During the
// scan's ~199 us (4 waves, 99% of the chip idle) the 384 GEMM blocks fill
// the idle CUs: ~60% of the GEMM cost hides under the scan.
//
// Scan recurrence (one wave per batch, verified round-0 machinery):
//   w_{t+1} = (w_t . Abar_t) * rsqrt(sum w_t^2) + c_t
// ---------------------------------------------------------------------------
__global__ __launch_bounds__(256) void fused_scan_gemm2_kernel(
    const float* __restrict__ x, const float* __restrict__ Wcomb,
    const float* __restrict__ biasC, float* __restrict__ Cc,
    const float* __restrict__ cBuf, float* __restrict__ wOut)
{
    __shared__ float As[32][132];
    __shared__ float Bs[32][132];

    if (blockIdx.x < 4) {
        // ------------------ scan path (threads 0..63 only) ------------------
        const int tid = threadIdx.x;
        if (tid >= 64) return;
        const int b = blockIdx.x;

        const float* At = Cc + (size_t)b * L_ * NC_ + 4 * tid;   // lane base
        const float* cb = cBuf + (size_t)b * L_ * 32 + (tid & 31);
        float*       wo = wOut + (size_t)b * L_ * 64 + tid;

        const int idx0 = 16 * (tid & 7);
        const int idxR = 32 * (tid & 7) + 28;    // octet TOP lane
        const bool selA = (tid >> 3) & 1;
        const bool selB = (tid >> 4) & 1;

        float4 areg[DPRE][4];
        float  creg[DPRE];

        #pragma unroll
        for (int j = 0; j < DPRE; ++j) {
            const float* ap = At + (size_t)j * NC_;
            #pragma unroll
            for (int q = 0; q < 4; ++q) areg[j][q] = *(const float4*)(ap + 256 * q);
            creg[j] = cb[j * 32];
        }

        float w = 0.f;   // w_0 = 0  (h_0 = 0)

        for (int t = 0; t < L_; t += DPRE) {
            #pragma unroll
            for (int j = 0; j < DPRE; ++j) {
                wo[(t + j) * 64] = w;

                float red = reduce32_to_lane31(w * w);

                const float wb0 = bpermute_f(idx0 + 0,  w);
                const float wb1 = bpermute_f(idx0 + 4,  w);
                const float wb2 = bpermute_f(idx0 + 8,  w);
                const float wb3 = bpermute_f(idx0 + 12, w);

                float p0, p1, p2, p3;
                {
                    const float4 a0 = areg[j][0], a1 = areg[j][1];
                    const float4 a2 = areg[j][2], a3 = areg[j][3];
                    p0 = fmaf(wb3, a0.w, fmaf(wb2, a0.z, fmaf(wb1, a0.y, wb0 * a0.x)));
                    p1 = fmaf(wb3, a1.w, fmaf(wb2, a1.z, fmaf(wb1, a1.y, wb0 * a1.x)));
                    p2 = fmaf(wb3, a2.w, fmaf(wb2, a2.z, fmaf(wb1, a2.y, wb0 * a2.x)));
                    p3 = fmaf(wb3, a3.w, fmaf(wb2, a3.z, fmaf(wb1, a3.y, wb0 * a3.x)));
                }

                p0 = octet_sum(p0);
                p1 = octet_sum(p1);
                p2 = octet_sum(p2);
                p3 = octet_sum(p3);

                const float m0 = bpermute_f(idxR, p0);
                const float m1 = bpermute_f(idxR, p1);
                const float m2 = bpermute_f(idxR, p2);
                const float m3 = bpermute_f(idxR, p3);
                const float t0 = selA ? m1 : m0;
                const float t1 = selA ? m3 : m2;
                const float m  = selB ? t1 : t0;

                const float n2 = readlane_f(red, 31);
                const float rn = rsqrtf(n2 + 1e-24f);
                w = fmaf(m, rn, creg[j]);

                int tn = t + j + DPRE;
                if (tn > L_ - 1) tn = L_ - 1;
                const float* ap = At + (size_t)tn * NC_;
                #pragma unroll
                for (int q = 0; q < 4; ++q) areg[j][q] = *(const float4*)(ap + 256 * q);
                creg[j] = cb[tn * 32];
            }
        }
        return;
    }

    // ------------------ GEMM part-2 path (cols 1024..2560) ------------------
    const int g  = blockIdx.x - 4;
    const int m0 = (g / 12) * 128;
    const int n0 = 1024 + (g % 12) * 128;
    gemm_tile_body(x, Wcomb, biasC, Cc, BT_, NC_, D_, m0, n0, As, Bs);
}

// ---------------------------------------------------------------------------
// Phase B: left = w/||w|| + u; y1[j] = sum_l left[l]*G[l*32+j] + bb[j],
// where G is C[bt*NC_ + 1024 ..2048).
// ---------------------------------------------------------------------------
__global__ __launch_bounds__(128) void phaseB_kernel(
    const float* __restrict__ Cc, const float* __restrict__ x,
    const float* __restrict__ wBuf, const float* __restrict__ bb,
    float* __restrict__ y1)
{
    __shared__ float lf[32];
    __shared__ float part[4][32];

    const int bt = blockIdx.x;
    const int tid = threadIdx.x;

    if (tid < 64) {
        const float wv = wBuf[(size_t)bt * 64 + tid];
        float red = reduce32_to_lane31(wv * wv);
        const float n2 = readlane_f(red, 31);
        const float rn = rsqrtf(n2 + 1e-24f);
        if (tid < 32)
            lf[tid] = fmaf(wv, rn, x[(size_t)bt * D_ + tid]);  // left = h + u
    }
    __syncthreads();

    const int j = tid & 31, q = tid >> 5;
    const float* Gp = Cc + (size_t)bt * NC_ + 1024;
    float p = 0.f;
    #pragma unroll
    for (int i = 0; i < 8; ++i)
        p = fmaf(lf[8 * q + i], Gp[(8 * q + i) * 32 + j], p);
    part[q][j] = p;
    __syncthreads();

    if (tid < 32)
        y1[bt * 32 + tid] = part[0][tid] + part[1][tid] + part[2][tid]
                          + part[3][tid] + bb[tid];
}

// ---------------------------------------------------------------------------
// Epilogue: y = y1 @ W_out + b_out; LayerNorm; gated residual with x.
// gate logits live in C[bt*NC_ + 2048 ..2560).
// ---------------------------------------------------------------------------
__global__ __launch_bounds__(256) void epilogue_kernel(
    const float* __restrict__ x, const float* __restrict__ y1buf,
    const float* __restrict__ Wout, const float* __restrict__ bout,
    const float* __restrict__ gamma, const float* __restrict__ beta,
    const float* __restrict__ Cc, float* __restrict__ out)
{
    __shared__ float ys[32];
    __shared__ float red1[4], red2[4];

    const int bt = blockIdx.x;
    const int tid = threadIdx.x;

    if (tid < 32) ys[tid] = y1buf[bt * 32 + tid];
    __syncthreads();

    float yv[2];
    #pragma unroll
    for (int q = 0; q < 2; ++q) {
        const int d = tid + q * 256;
        float acc = bout[d];
        #pragma unroll
        for (int j = 0; j < 32; ++j)
            acc = fmaf(ys[j], Wout[j * D_ + d], acc);
        yv[q] = acc;
    }

    float s1 = yv[0] + yv[1];
    float s2 = yv[0] * yv[0] + yv[1] * yv[1];
    #pragma unroll
    for (int m = 1; m <= 32; m <<= 1) {
        s1 += __shfl_xor(s1, m);
        s2 += __shfl_xor(s2, m);
    }
    const int wid = tid >> 6;
    if ((tid & 63) == 0) { red1[wid] = s1; red2[wid] = s2; }
    __syncthreads();
    const float S1 = red1[0] + red1[1] + red1[2] + red1[3];
    const float S2 = red2[0] + red2[1] + red2[2] + red2[3];
    const float mu  = S1 * (1.f / (float)D_);
    const float var = S2 * (1.f / (float)D_) - mu * mu;
    const float rstd = rsqrtf(var + 1e-6f);

    #pragma unroll
    for (int q = 0; q < 2; ++q) {
        const int d = tid + q * 256;
        const size_t gi = (size_t)bt * D_ + d;
        const float yn = (yv[q] - mu) * rstd * gamma[d] + beta[d];
        const float z = Cc[(size_t)bt * NC_ + 2048 + d];
        const float g = 1.f / (1.f + expf(-z));
        const float xv = x[gi];
        out[gi] = g * yn + (1.f - g) * xv;
    }
}

// ---------------------------------------------------------------------------
extern "C" void kernel_launch(void* const* d_in, const int* in_sizes, int n_in,
                              void* d_out, int out_size, void* d_ws, size_t ws_size,
                              hipStream_t stream)
{
    const float* x        = (const float*)d_in[0];
    const float* W_site   = (const float*)d_in[1];
    const float* b_site   = (const float*)d_in[2];
    const float* W_bridge = (const float*)d_in[3];
    const float* b_bridge = (const float*)d_in[4];
    const float* W_out    = (const float*)d_in[5];
    const float* b_out    = (const float*)d_in[6];
    const float* gamma    = (const float*)d_in[7];
    const float* beta     = (const float*)d_in[8];
    const float* W_gate   = (const float*)d_in[9];
    const float* b_gate   = (const float*)d_in[10];
    float* out = (float*)d_out;

    float* ws = (float*)d_ws;
    float* Wcomb = ws;                            //   512*2560 = 1,310,720 f
    float* biasC = Wcomb + (size_t)512 * NC_;     //        2,560 f
    float* Cc    = biasC + NC_;                   // 4096*2560 = 10,485,760 f (42 MB)
    float* cBuf  = Cc    + (size_t)BT_ * NC_;     //      131,072 f
    float* wBuf  = cBuf  + (size_t)BT_ * 32;      //      262,144 f
    float* y1    = wBuf  + (size_t)BT_ * 64;      //      131,072 f

    // 0. fold weights: [WA_perm | WW | W_gate] + fused bias
    buildW_kernel<<<dim3(513), dim3(256), 0, stream>>>(
        W_site, b_site, W_bridge, W_gate, b_gate, Wcomb, biasC);

    // 1. GEMM part 1: C cols [0,1024) = AbarI   [4096 x 1024, K=512]
    gemm_bias_kernel<<<dim3(8, BT_ / 128), dim3(256), 0, stream>>>(
        x, Wcomb, biasC, Cc, BT_, NC_, D_);

    // 2. c vectors: c = u . Abar  (fully parallel)
    cvec_kernel<<<dim3(BT_ / 4), dim3(256), 0, stream>>>(Cc, x, cBuf);

    // 3. FUSED: scan (blocks 0..3) + GEMM part 2 (cols 1024..2560, blocks
    //    4..387) -- part 2 hides under the scan's 199 us on idle CUs.
    fused_scan_gemm2_kernel<<<dim3(4 + 12 * (BT_ / 128)), dim3(256), 0, stream>>>(
        x, Wcomb, biasC, Cc, cBuf, wBuf);

    // 4. phase B: y1 = left . G + bb
    phaseB_kernel<<<dim3(BT_), dim3(128), 0, stream>>>(
        Cc, x, wBuf, b_bridge, y1);

    // 5. epilogue: out-proj + LN + gated residual (gate from C)
    epilogue_kernel<<<dim3(BT_), dim3(256), 0, stream>>>(
        x, y1, W_out, b_out, gamma, beta, Cc, out);
}